// Round 8
// baseline (222.457 us; speedup 1.0000x reference)
//
#include <hip/hip_runtime.h>
#include <hip/hip_bf16.h>

// Problem constants (from reference)
#define BATCH 8
#define NH    8
#define HD    32
#define WIN   512    // 64 x 8 tokens per vertical-stripe window
#define DIM   256
#define RESO  64
#define SEQL  4096
#define VSTRIDE 522  // Vt padded token stride (bf16): dword stride 261 -> bank step 5 (odd)
#define WPAD  264    // proj W LDS row stride (bf16 elements)

#define LOG2E 1.44269504088896340736f

extern "C" __device__ float __ocml_native_exp2_f32(float);   // raw v_exp_f32

typedef __attribute__((ext_vector_type(8))) short short8;   // 8 bf16 (4 VGPRs) MFMA A/B frag
typedef __attribute__((ext_vector_type(4))) float floatx4;  // MFMA C/D frag

__device__ __forceinline__ unsigned short f2bf(float f) {
    union { float f; unsigned int i; } x; x.f = f;
    unsigned int r = x.i + 0x7fff + ((x.i >> 16) & 1);   // round-to-nearest-even
    return (unsigned short)(r >> 16);
}
__device__ __forceinline__ unsigned int pk2(float lo, float hi) {      // RNE pack
    return ((unsigned int)f2bf(hi) << 16) | (unsigned int)f2bf(lo);
}
__device__ __forceinline__ unsigned int pk2t(float lo, float hi) {     // truncation pack, 1 v_perm
    union { float f; unsigned int i; } a, b; a.f = lo; b.f = hi;
    return __builtin_amdgcn_perm(b.i, a.i, 0x07060302);                // {hi[3],hi[2],lo[3],lo[2]}
}
__device__ __forceinline__ void unp2(unsigned int u, float& lo, float& hi) {
    union { unsigned int i; float f; } a, b;
    a.i = u << 16; b.i = u & 0xffff0000u;
    lo = a.f; hi = b.f;
}

union FragU {
    unsigned int  u[4];
    unsigned short us[8];
    short8        s;
    ushort4       v4[2];
};

// ---------------------------------------------------------------------------
// MFMA flash attention + LePE. Grid: 512 blocks (64 win x 8 heads) x 512 thr
// (8 waves). Wave w owns query rows w*64..w*64+63 (4 q-tiles of 16).
// Q pre-scaled by scale*log2e -> scores in log2 domain; p = v_exp_f32.
// S^T via mfma_16x16x32 (A=K swizzled LDS, B=Q^T); exp'd P feeds PV mfma
// directly from registers. LePE 3x3 epilogue reads V fp32 from GLOBAL
// (float4 per tap, L2-hot) and conv weights from LDS transposed [tap][ch].
// ---------------------------------------------------------------------------
__global__ __launch_bounds__(512, 4)
void attn_mfma_kernel(const float* __restrict__ qkv,
                      const float* __restrict__ scale_p,
                      const float* __restrict__ conv_w,
                      const float* __restrict__ conv_b,
                      unsigned short* __restrict__ X)
{
    __shared__ alignas(16) unsigned short Klds[WIN * HD];      // swizzled 16B chunks
    __shared__ alignas(16) unsigned short Vt[HD * VSTRIDE];    // V^T, padded
    __shared__ alignas(16) float cwT[9 * HD];                  // [tap][ch]
    __shared__ float cb[HD];

    const int wh   = blockIdx.x;
    const int bw   = wh >> 3;        // global window 0..63
    const int head = wh & 7;
    const int b    = bw >> 3;
    const int wx   = bw & 7;
    const int tid  = threadIdx.x;

    const float scale = scale_p[0] * LOG2E;    // log2-domain logits
    const size_t plane = (size_t)BATCH * SEQL * DIM;
    const float* qg = qkv;
    const float* kg = qkv + plane;
    const float* vg = qkv + 2 * plane;

    // ---- Stage K (bf16 trunc, XOR-swizzled 16B chunks) ----
    for (int idx = tid; idx < WIN * 4; idx += 512) {
        const int t = idx >> 2, c8 = idx & 3;
        const size_t goff = ((size_t)b * SEQL + (size_t)(t >> 3) * RESO + wx * 8 + (t & 7)) * DIM
                          + head * HD + c8 * 8;
        const float4 k0 = *(const float4*)(kg + goff);
        const float4 k1 = *(const float4*)(kg + goff + 4);
        uint4 pk;
        pk.x = pk2t(k0.x, k0.y); pk.y = pk2t(k0.z, k0.w);
        pk.z = pk2t(k1.x, k1.y); pk.w = pk2t(k1.z, k1.w);
        const int p = c8 ^ ((t >> 1) & 3);
        *(uint4*)&Klds[t * HD + p * 8] = pk;
    }
    // ---- Stage V^T: vector loads, token-consecutive-lane b16 writes (2-way free) ----
    for (int idx = tid; idx < WIN * 4; idx += 512) {
        const int t = idx & 511, seg = idx >> 9;     // lanes -> consecutive tokens
        const size_t goff = ((size_t)b * SEQL + (size_t)(t >> 3) * RESO + wx * 8 + (t & 7)) * DIM
                          + head * HD + seg * 8;
        const float4 v0 = *(const float4*)(vg + goff);
        const float4 v1 = *(const float4*)(vg + goff + 4);
        const int ch0 = seg * 8;
        Vt[(ch0 + 0) * VSTRIDE + t] = f2bf(v0.x);
        Vt[(ch0 + 1) * VSTRIDE + t] = f2bf(v0.y);
        Vt[(ch0 + 2) * VSTRIDE + t] = f2bf(v0.z);
        Vt[(ch0 + 3) * VSTRIDE + t] = f2bf(v0.w);
        Vt[(ch0 + 4) * VSTRIDE + t] = f2bf(v1.x);
        Vt[(ch0 + 5) * VSTRIDE + t] = f2bf(v1.y);
        Vt[(ch0 + 6) * VSTRIDE + t] = f2bf(v1.z);
        Vt[(ch0 + 7) * VSTRIDE + t] = f2bf(v1.w);
    }
    if (tid < 9 * HD) {                             // cw transposed: [tap][ch]
        const int wof = tid >> 5, ch = tid & 31;
        cwT[wof * HD + ch] = conv_w[head * HD * 9 + ch * 9 + wof];
    }
    if (tid < HD) cb[tid] = conv_b[head * HD + tid];
    __syncthreads();

    const int lane = tid & 63, wid = tid >> 6;
    const int q4 = lane >> 4, nn = lane & 15;
    const int qbase = wid * 64;
    const bool mwin = (wx == 7);

    // mask add (only stripe wx==7): key group vs query group, lane-constant
    float mk[4];
    #pragma unroll
    for (int r = 0; r < 4; ++r) {
        const bool kgrp = (((q4 * 4 + r) & 7) < 4);
        const bool qgrp = ((nn & 7) < 4);
        mk[r] = (kgrp != qgrp) ? (-100.f * LOG2E) : 0.f;
    }

    // ---- Q B-frags (4 q-tiles), pre-scaled (log2e folded), bf16 trunc ----
    short8 qf[4];
    #pragma unroll
    for (int qq = 0; qq < 4; ++qq) {
        const int t = qbase + qq * 16 + nn;
        const size_t goff = ((size_t)b * SEQL + (size_t)(t >> 3) * RESO + wx * 8 + (t & 7)) * DIM
                          + head * HD + q4 * 8;
        const float4 a = *(const float4*)(qg + goff);
        const float4 c = *(const float4*)(qg + goff + 4);
        FragU f;
        f.u[0] = pk2t(a.x * scale, a.y * scale);
        f.u[1] = pk2t(a.z * scale, a.w * scale);
        f.u[2] = pk2t(c.x * scale, c.y * scale);
        f.u[3] = pk2t(c.z * scale, c.w * scale);
        qf[qq] = f.s;
    }

    floatx4 acc[4][2];
    #pragma unroll
    for (int qq = 0; qq < 4; ++qq) {
        acc[qq][0] = (floatx4){0.f, 0.f, 0.f, 0.f};
        acc[qq][1] = (floatx4){0.f, 0.f, 0.f, 0.f};
    }
    float rs[4] = {0.f, 0.f, 0.f, 0.f};
    const floatx4 zf = (floatx4){0.f, 0.f, 0.f, 0.f};

    // ---- main K loop: 16 chunks of 32 keys (2 j-tiles each) ----
    for (int kc = 0; kc < 16; ++kc) {
        short8 kf0, kf1;
        {
            const int t0 = (2 * kc) * 16 + nn;
            const int t1 = (2 * kc + 1) * 16 + nn;
            kf0 = *(const short8*)&Klds[t0 * HD + (q4 ^ ((t0 >> 1) & 3)) * 8];
            kf1 = *(const short8*)&Klds[t1 * HD + (q4 ^ ((t1 >> 1) & 3)) * 8];
        }
        short8 vf[2];
        #pragma unroll
        for (int nt = 0; nt < 2; ++nt) {
            const int ch = nt * 16 + nn;
            FragU f;
            f.v4[0] = *(const ushort4*)&Vt[ch * VSTRIDE + kc * 32 + q4 * 4];
            f.v4[1] = *(const ushort4*)&Vt[ch * VSTRIDE + kc * 32 + 16 + q4 * 4];
            vf[nt] = f.s;
        }
        #pragma unroll
        for (int qq = 0; qq < 4; ++qq) {
            floatx4 s0 = __builtin_amdgcn_mfma_f32_16x16x32_bf16(kf0, qf[qq], zf, 0, 0, 0);
            floatx4 s1 = __builtin_amdgcn_mfma_f32_16x16x32_bf16(kf1, qf[qq], zf, 0, 0, 0);
            if (mwin) {                              // wave-uniform branch (1/8 blocks)
                #pragma unroll
                for (int r = 0; r < 4; ++r) { s0[r] += mk[r]; s1[r] += mk[r]; }
            }
            float p[8];
            #pragma unroll
            for (int r = 0; r < 4; ++r) {
                p[r]     = __ocml_native_exp2_f32(s0[r]);   // single v_exp_f32
                p[4 + r] = __ocml_native_exp2_f32(s1[r]);
            }
            rs[qq] += ((p[0] + p[1]) + (p[2] + p[3])) + ((p[4] + p[5]) + (p[6] + p[7]));
            FragU pf;                                // truncation pack: 1 v_perm each
            pf.u[0] = pk2t(p[0], p[1]);
            pf.u[1] = pk2t(p[2], p[3]);
            pf.u[2] = pk2t(p[4], p[5]);
            pf.u[3] = pk2t(p[6], p[7]);
            acc[qq][0] = __builtin_amdgcn_mfma_f32_16x16x32_bf16(vf[0], pf.s, acc[qq][0], 0, 0, 0);
            acc[qq][1] = __builtin_amdgcn_mfma_f32_16x16x32_bf16(vf[1], pf.s, acc[qq][1], 0, 0, 0);
        }
    }

    // ---- row sums across quads; lane-aligned with PV C-layout columns ----
    float inv[4];
    #pragma unroll
    for (int qq = 0; qq < 4; ++qq) {
        float v = rs[qq];
        v += __shfl_xor(v, 16);
        v += __shfl_xor(v, 32);
        inv[qq] = 1.0f / v;
    }

    // ---- epilogue: normalize, +conv bias, LePE 3x3 (V fp32 from global,
    //      cw float4 from LDS), store bf16 X ----
    #pragma unroll
    for (int qq = 0; qq < 4; ++qq) {
        const int t = qbase + qq * 16 + nn;
        const int h = t >> 3, wi = t & 7;
        float o[2][4];
        #pragma unroll
        for (int nt = 0; nt < 2; ++nt) {
            const int chb = nt * 16 + q4 * 4;
            #pragma unroll
            for (int r = 0; r < 4; ++r)
                o[nt][r] = acc[qq][nt][r] * inv[qq] + cb[chb + r];
        }
        #pragma unroll
        for (int dh = -1; dh <= 1; ++dh) {
            const int hh = h + dh;
            if (hh < 0 || hh >= RESO) continue;
            #pragma unroll
            for (int dw = -1; dw <= 1; ++dw) {
                const int ww = wi + dw;
                if (ww < 0 || ww >= 8) continue;
                const int wof = (dh + 1) * 3 + (dw + 1);
                const size_t gv = ((size_t)b * SEQL + (size_t)hh * RESO + wx * 8 + ww) * DIM
                                + head * HD;
                #pragma unroll
                for (int nt = 0; nt < 2; ++nt) {
                    const int chb = nt * 16 + q4 * 4;
                    const float4 vv = *(const float4*)(vg + gv + chb);
                    const float4 wv = *(const float4*)&cwT[wof * HD + chb];
                    o[nt][0] += wv.x * vv.x;
                    o[nt][1] += wv.y * vv.y;
                    o[nt][2] += wv.z * vv.z;
                    o[nt][3] += wv.w * vv.w;
                }
            }
        }
        #pragma unroll
        for (int nt = 0; nt < 2; ++nt) {
            const int chb = nt * 16 + q4 * 4;
            ushort4 st;
            st.x = f2bf(o[nt][0]); st.y = f2bf(o[nt][1]);
            st.z = f2bf(o[nt][2]); st.w = f2bf(o[nt][3]);
            *(ushort4*)&X[((size_t)bw * WIN + t) * DIM + head * HD + chb] = st;
        }
    }
}

// ---------------------------------------------------------------------------
// Kernel 2: MFMA projection GEMM  out = X @ W^T + b, CSwin2img permuted rows.
// Grid: 512 blocks (128 m-blocks x 4 n-blocks) x 256 thr (4 waves).
// kk loop fully unrolled so all global X b128 loads issue early.
// ---------------------------------------------------------------------------
__global__ __launch_bounds__(256, 4)
void proj_mfma_kernel(const unsigned short* __restrict__ X,
                      const float* __restrict__ pw,
                      const float* __restrict__ pb,
                      float* __restrict__ out)
{
    __shared__ alignas(16) unsigned short Wl[64 * WPAD];   // 33.8 KB

    const int bx   = blockIdx.x;
    const int mblk = bx >> 2;            // 0..127 -> 256 tokens each
    const int nblk = bx & 3;             // 0..3   -> 64 channels each
    const int tid  = threadIdx.x;
    const int n0   = nblk * 64;

    // ---- stage W[n0..n0+63][0..255] -> bf16 LDS (4 threads per row) ----
    {
        const int row = tid >> 2;
        const int cb0 = (tid & 3) * 64;
        #pragma unroll
        for (int c = 0; c < 64; c += 8) {
            const float4 w0 = *(const float4*)&pw[(size_t)(n0 + row) * DIM + cb0 + c];
            const float4 w1 = *(const float4*)&pw[(size_t)(n0 + row) * DIM + cb0 + c + 4];
            uint4 pk;
            pk.x = pk2(w0.x, w0.y); pk.y = pk2(w0.z, w0.w);
            pk.z = pk2(w1.x, w1.y); pk.w = pk2(w1.z, w1.w);
            *(uint4*)&Wl[row * WPAD + cb0 + c] = pk;
        }
    }
    __syncthreads();

    const int lane = tid & 63, wid = tid >> 6;
    const int q4 = lane >> 4, nn = lane & 15;
    const int mwave = mblk * 256 + wid * 64;     // 64 tokens per wave

    floatx4 acc[4][4];                            // [nt][mt]
    #pragma unroll
    for (int i = 0; i < 4; ++i)
        #pragma unroll
        for (int j = 0; j < 4; ++j)
            acc[i][j] = (floatx4){0.f, 0.f, 0.f, 0.f};

    #pragma unroll
    for (int kk = 0; kk < 8; ++kk) {
        short8 af[4], bf[4];
        #pragma unroll
        for (int nt = 0; nt < 4; ++nt)
            af[nt] = *(const short8*)&Wl[(nt * 16 + nn) * WPAD + kk * 32 + q4 * 8];
        #pragma unroll
        for (int mt = 0; mt < 4; ++mt) {
            const int m = mwave + mt * 16 + nn;
            bf[mt] = *(const short8*)&X[(size_t)m * DIM + kk * 32 + q4 * 8];
        }
        #pragma unroll
        for (int nt = 0; nt < 4; ++nt)
            #pragma unroll
            for (int mt = 0; mt < 4; ++mt)
                acc[nt][mt] = __builtin_amdgcn_mfma_f32_16x16x32_bf16(af[nt], bf[mt], acc[nt][mt], 0, 0, 0);
    }

    // ---- bias + permuted store (float4 per lane per tile) ----
    float4 bias[4];
    #pragma unroll
    for (int nt = 0; nt < 4; ++nt)
        bias[nt] = *(const float4*)&pb[n0 + nt * 16 + q4 * 4];

    size_t rowoff[4];
    #pragma unroll
    for (int mt = 0; mt < 4; ++mt) {
        const int m  = mwave + mt * 16 + nn;
        const int bw = m >> 9, t = m & 511;
        const int bb = bw >> 3, wx = bw & 7, hh = t >> 3, wi = t & 7;
        rowoff[mt] = ((size_t)bb * SEQL + (size_t)hh * RESO + wx * 8 + wi) * DIM;
    }

    #pragma unroll
    for (int nt = 0; nt < 4; ++nt)
        #pragma unroll
        for (int mt = 0; mt < 4; ++mt) {
            float4 v;
            v.x = acc[nt][mt][0] + bias[nt].x;
            v.y = acc[nt][mt][1] + bias[nt].y;
            v.z = acc[nt][mt][2] + bias[nt].z;
            v.w = acc[nt][mt][3] + bias[nt].w;
            *(float4*)&out[rowoff[mt] + n0 + nt * 16 + q4 * 4] = v;
        }
}

extern "C" void kernel_launch(void* const* d_in, const int* in_sizes, int n_in,
                              void* d_out, int out_size, void* d_ws, size_t ws_size,
                              hipStream_t stream)
{
    const float* qkv    = (const float*)d_in[0];
    const float* scale  = (const float*)d_in[1];
    const float* proj_w = (const float*)d_in[2];
    const float* proj_b = (const float*)d_in[3];
    const float* conv_w = (const float*)d_in[4];
    const float* conv_b = (const float*)d_in[5];

    unsigned short* X = (unsigned short*)d_ws;   // 64*512*256 bf16 = 16 MiB

    attn_mfma_kernel<<<dim3(BATCH * NH * 8), dim3(512), 0, stream>>>(
        qkv, scale, conv_w, conv_b, X);

    proj_mfma_kernel<<<dim3(512), dim3(256), 0, stream>>>(
        X, proj_w, proj_b, (float*)d_out);
}